// Round 17
// baseline (218.858 us; speedup 1.0000x reference)
//
#include <hip/hip_runtime.h>
#include <hip/hip_bf16.h>

// Shapes (fixed): B=4, N=2048, C=512, H=8, D=64, GROUPS=8, C/G=64
typedef __attribute__((ext_vector_type(8))) short bf16x8;
typedef __attribute__((ext_vector_type(4))) float f32x4;

__device__ __forceinline__ float bfu2f(unsigned int u) {
    return __uint_as_float(u << 16);
}
__device__ __forceinline__ unsigned short f2bfu(float f) {
    unsigned int u = __float_as_uint(f);
    u += 0x7fffu + ((u >> 16) & 1u);   // RNE
    return (unsigned short)(u >> 16);
}

// ---------------- all fp32->bf16 conversions + bias gather, one launch ----------------
__global__ __launch_bounds__(256) void cvt_all(
    const float* __restrict__ x, unsigned short* __restrict__ xb,
    const float* __restrict__ pe, unsigned short* __restrict__ peb,
    const float* __restrict__ w0, unsigned short* __restrict__ d0,
    const float* __restrict__ w1, unsigned short* __restrict__ d1,
    const float* __restrict__ w2, unsigned short* __restrict__ d2,
    const float* __restrict__ w3, unsigned short* __restrict__ d3,
    const float* __restrict__ c1bias, const float* __restrict__ c2bias,
    float* __restrict__ biasws) {
    const int tid = threadIdx.x;
    if (blockIdx.x == 0) {
        if (tid < 128) ((float4*)biasws)[tid] = ((const float4*)c1bias)[tid];
        else ((float4*)biasws)[tid] = ((const float4*)c2bias)[tid - 128];
    }
    int i = blockIdx.x * 256 + tid;
    const int stride = gridDim.x * 256;
    for (; i < 1441792; i += stride) {
        if (i < 1048576) {
            float4 v = reinterpret_cast<const float4*>(x)[i];
            ushort4 o;
            o.x = f2bfu(v.x); o.y = f2bfu(v.y); o.z = f2bfu(v.z); o.w = f2bfu(v.w);
            reinterpret_cast<ushort4*>(xb)[i] = o;
            float4 u = reinterpret_cast<const float4*>(pe)[i];
            ushort4 p;
            p.x = f2bfu(u.x); p.y = f2bfu(u.y); p.z = f2bfu(u.z); p.w = f2bfu(u.w);
            reinterpret_cast<ushort4*>(peb)[i] = p;
        } else {
            int j = i - 1048576;
            const float* s; unsigned short* d;
            if (j < 196608)      { s = w0; d = d0; }
            else if (j < 262144) { s = w1; d = d1; j -= 196608; }
            else if (j < 327680) { s = w2; d = d2; j -= 262144; }
            else                 { s = w3; d = d3; j -= 327680; }
            float4 v = reinterpret_cast<const float4*>(s)[j];
            ushort4 o;
            o.x = f2bfu(v.x); o.y = f2bfu(v.y); o.z = f2bfu(v.z); o.w = f2bfu(v.w);
            reinterpret_cast<ushort4*>(d)[j] = o;
        }
    }
}

// ---------------- generic NT GEMM, 3-buffer rotation + counted vmcnt [R15-verified] -----
// EPI: 0 = conv pair (bf16 out, +bias, GN stats atomics via C1), 3 = proj (f32 out, +bias)
template <int EPI>
__global__ __launch_bounds__(256) void gemm_nt(
    const unsigned short* __restrict__ A, const unsigned short* __restrict__ B,
    void* __restrict__ C0, void* __restrict__ C1, void* __restrict__ C2,
    const float* __restrict__ bias, int K, long sA, long sB, long sC,
    int nx, int ny) {
    __shared__ unsigned short As[3][128 * 32];
    __shared__ unsigned short Bs[3][128 * 32];
    int lin = blockIdx.x;
    const int qsw = gridDim.x >> 3;
    lin = (lin & 7) * qsw + (lin >> 3);          // bijective XCD swizzle (grid % 8 == 0)
    const int bx = lin % nx;
    const int t2 = lin / nx;
    const int by = t2 % ny;
    const int bz = t2 / ny;
    const int tid = threadIdx.x;
    const int l = tid & 63, w = tid >> 6;
    const int wr = w >> 1, wc = w & 1, lr = l & 15, lh = l >> 4;
    const int m0 = by * 128, n0 = bx * 128;
    A += (size_t)bz * sA;
    B += (size_t)bz * sB;
    f32x4 acc[4][4] = {};

    const int srow = l >> 2, sslot = l & 3;
    auto stage = [&](int bufi, int k0) {
#pragma unroll
        for (int i = 0; i < 2; i++) {
            const int row = w * 32 + i * 16 + srow;
            const int cs = (sslot ^ (row & 3)) * 8;
            const int ldsoff = (w * 32 + i * 16) * 32;
            __builtin_amdgcn_global_load_lds(
                (const __attribute__((address_space(1))) void*)(A + (size_t)(m0 + row) * K + k0 + cs),
                (__attribute__((address_space(3))) void*)&As[bufi][ldsoff], 16, 0, 0);
            __builtin_amdgcn_global_load_lds(
                (const __attribute__((address_space(1))) void*)(B + (size_t)(n0 + row) * K + k0 + cs),
                (__attribute__((address_space(3))) void*)&Bs[bufi][ldsoff], 16, 0, 0);
        }
    };

    const int nks = K >> 5;
    stage(0, 0);
    stage(1, 32);

    const int colA = (lh ^ (lr & 3)) << 3;
    int cur = 0;
    for (int ks = 0; ks < nks; ks++) {
        if (ks == nks - 1)
            asm volatile("s_waitcnt vmcnt(0) lgkmcnt(0)" ::: "memory");
        else
            asm volatile("s_waitcnt vmcnt(4) lgkmcnt(0)" ::: "memory");
        __builtin_amdgcn_s_barrier();
        __builtin_amdgcn_sched_barrier(0);
        if (ks + 2 < nks) stage((ks + 2) % 3, (ks + 2) << 5);
        bf16x8 af[4], bfr[4];
#pragma unroll
        for (int i = 0; i < 4; i++)
            af[i] = *reinterpret_cast<const bf16x8*>(&As[cur][(wr * 64 + i * 16 + lr) * 32 + colA]);
#pragma unroll
        for (int i = 0; i < 4; i++)
            bfr[i] = *reinterpret_cast<const bf16x8*>(&Bs[cur][(wc * 64 + i * 16 + lr) * 32 + colA]);
        __builtin_amdgcn_s_setprio(1);
#pragma unroll
        for (int mi = 0; mi < 4; mi++)
#pragma unroll
            for (int ni = 0; ni < 4; ni++)
                acc[mi][ni] = __builtin_amdgcn_mfma_f32_16x16x32_bf16(af[mi], bfr[ni], acc[mi][ni], 0, 0, 0);
        __builtin_amdgcn_s_setprio(0);
        cur = (cur + 1) % 3;
    }

    float sgn = 0.f, qgn = 0.f;   // fused GN partial stats (EPI==0)
#pragma unroll
    for (int mi = 0; mi < 4; mi++) {
#pragma unroll
        for (int ni = 0; ni < 4; ni++) {
#pragma unroll
            for (int r = 0; r < 4; r++) {
                const int row = m0 + wr * 64 + mi * 16 + lh * 4 + r;
                const int col = n0 + wc * 64 + ni * 16 + lr;
                float v = acc[mi][ni][r];
                if constexpr (EPI == 0) {
                    v += bias[bz * 512 + col];
                    sgn += v; qgn += v * v;
                    ((unsigned short*)C0)[(size_t)bz * sC + (size_t)row * 512 + col] = f2bfu(v);
                } else {
                    ((float*)C0)[(size_t)row * 512 + col] = v + bias[col];
                }
            }
        }
    }
    if constexpr (EPI == 0) {
        // wave holds one (b,g): b = by>>4, g = bx*2+wc
#pragma unroll
        for (int s = 1; s < 64; s <<= 1) {
            sgn += __shfl_xor(sgn, s);
            qgn += __shfl_xor(qgn, s);
        }
        if (l == 0) {
            const int bg = ((by >> 4) << 3) + bx * 2 + wc;
            float* part = (float*)C1;
            atomicAdd(&part[(bz * 32 + bg) * 2 + 0], sgn);
            atomicAdd(&part[(bz * 32 + bg) * 2 + 1], qgn);
        }
    }
}

// ---------------- pe GEMM: 256x128 tile, sigmoid epilogue (dedicated kernel) ------------
// grid 512 = nx16 (k-tiles) x ny8 (q-tiles of 256) x nz4 (batch), XCD-swizzled.
// 4 waves in 4x1: wave w owns rows [64w,64w+64) x all 128 cols.  acc[4][8].
// Staging: A 4 instrs/wave (rows 64w..+64), B 2 instrs/wave (rows 32w..+32); 3-buffer
// rotation, steady-state vmcnt(6) (= one later 6-load stage in flight).
__global__ __launch_bounds__(256) void gemm_pe(
    const unsigned short* __restrict__ A, const unsigned short* __restrict__ B,
    unsigned short* __restrict__ C) {
    __shared__ unsigned short As[3][256 * 32];
    __shared__ unsigned short Bs[3][128 * 32];
    int lin = blockIdx.x;
    lin = (lin & 7) * 64 + (lin >> 3);           // 512 = 8*64
    const int bx = lin % 16;
    const int t2 = lin / 16;
    const int by = t2 % 8;
    const int bz = t2 / 8;
    const int tid = threadIdx.x;
    const int l = tid & 63, w = tid >> 6;
    const int lr = l & 15, lh = l >> 4;
    const int m0 = by * 256, n0 = bx * 128;
    A += (size_t)bz * 1048576;
    B += (size_t)bz * 1048576;
    f32x4 acc[4][8] = {};

    const int srow = l >> 2, sslot = l & 3;
    auto stage = [&](int bufi, int k0) {
#pragma unroll
        for (int i = 0; i < 4; i++) {            // A: rows 64w .. 64w+64
            const int row = w * 64 + i * 16 + srow;
            const int cs = (sslot ^ (row & 3)) * 8;
            const int ldsoff = (w * 64 + i * 16) * 32;
            __builtin_amdgcn_global_load_lds(
                (const __attribute__((address_space(1))) void*)(A + (size_t)(m0 + row) * 512 + k0 + cs),
                (__attribute__((address_space(3))) void*)&As[bufi][ldsoff], 16, 0, 0);
        }
#pragma unroll
        for (int i = 0; i < 2; i++) {            // B: rows 32w .. 32w+32
            const int row = w * 32 + i * 16 + srow;
            const int cs = (sslot ^ (row & 3)) * 8;
            const int ldsoff = (w * 32 + i * 16) * 32;
            __builtin_amdgcn_global_load_lds(
                (const __attribute__((address_space(1))) void*)(B + (size_t)(n0 + row) * 512 + k0 + cs),
                (__attribute__((address_space(3))) void*)&Bs[bufi][ldsoff], 16, 0, 0);
        }
    };

    stage(0, 0);
    stage(1, 32);

    const int colA = (lh ^ (lr & 3)) << 3;
    int cur = 0;
    for (int ks = 0; ks < 16; ks++) {
        if (ks == 15)
            asm volatile("s_waitcnt vmcnt(0) lgkmcnt(0)" ::: "memory");
        else
            asm volatile("s_waitcnt vmcnt(6) lgkmcnt(0)" ::: "memory");
        __builtin_amdgcn_s_barrier();
        __builtin_amdgcn_sched_barrier(0);
        if (ks + 2 < 16) stage((ks + 2) % 3, (ks + 2) << 5);
        bf16x8 af[4], bfr[8];
#pragma unroll
        for (int i = 0; i < 4; i++)
            af[i] = *reinterpret_cast<const bf16x8*>(&As[cur][(w * 64 + i * 16 + lr) * 32 + colA]);
#pragma unroll
        for (int i = 0; i < 8; i++)
            bfr[i] = *reinterpret_cast<const bf16x8*>(&Bs[cur][(i * 16 + lr) * 32 + colA]);
        __builtin_amdgcn_s_setprio(1);
#pragma unroll
        for (int mi = 0; mi < 4; mi++)
#pragma unroll
            for (int ni = 0; ni < 8; ni++)
                acc[mi][ni] = __builtin_amdgcn_mfma_f32_16x16x32_bf16(af[mi], bfr[ni], acc[mi][ni], 0, 0, 0);
        __builtin_amdgcn_s_setprio(0);
        cur = (cur + 1) % 3;
    }

    unsigned short* Cp = C + (size_t)bz * 4194304;
#pragma unroll
    for (int mi = 0; mi < 4; mi++) {
#pragma unroll
        for (int ni = 0; ni < 8; ni++) {
#pragma unroll
            for (int r = 0; r < 4; r++) {
                const int row = m0 + w * 64 + mi * 16 + lh * 4 + r;
                const int col = n0 + ni * 16 + lr;
                const float sg = 1.0f / (1.0f + __expf(-acc[mi][ni][r]));
                Cp[(size_t)row * 2048 + col] = f2bfu(sg);
            }
        }
    }
}

// ---------------- qkv GEMM [R16-verified] ----------------
__global__ __launch_bounds__(256) void gemm_qkv(
    const unsigned short* __restrict__ A, const unsigned short* __restrict__ B,
    unsigned short* __restrict__ qbuf, unsigned short* __restrict__ kbuf,
    unsigned short* __restrict__ vtb) {
    __shared__ unsigned short pool[24576];       // As = pool[0..12287], Bs = pool[12288..]
    int lin = blockIdx.x;
    lin = (lin & 7) * 96 + (lin >> 3);           // 768 = 8*96
    const int bx = lin % 12;
    const int by = lin / 12;
    const int tid = threadIdx.x;
    const int l = tid & 63, w = tid >> 6;
    const int wr = w >> 1, wc = w & 1, lr = l & 15, lh = l >> 4;
    const int m0 = by * 128, n0 = bx * 128;
    f32x4 acc[4][4] = {};

    const int srow = l >> 2, sslot = l & 3;
    auto stage = [&](int bufi, int k0) {
#pragma unroll
        for (int i = 0; i < 2; i++) {
            const int row = w * 32 + i * 16 + srow;
            const int cs = (sslot ^ (row & 3)) * 8;
            const int ldsoff = bufi * 4096 + (w * 32 + i * 16) * 32;
            __builtin_amdgcn_global_load_lds(
                (const __attribute__((address_space(1))) void*)(A + (size_t)(m0 + row) * 512 + k0 + cs),
                (__attribute__((address_space(3))) void*)&pool[ldsoff], 16, 0, 0);
            __builtin_amdgcn_global_load_lds(
                (const __attribute__((address_space(1))) void*)(B + (size_t)(n0 + row) * 512 + k0 + cs),
                (__attribute__((address_space(3))) void*)&pool[12288 + ldsoff], 16, 0, 0);
        }
    };

    stage(0, 0);
    stage(1, 32);

    const int colA = (lh ^ (lr & 3)) << 3;
    int cur = 0;
    for (int ks = 0; ks < 16; ks++) {
        if (ks == 15)
            asm volatile("s_waitcnt vmcnt(0) lgkmcnt(0)" ::: "memory");
        else
            asm volatile("s_waitcnt vmcnt(4) lgkmcnt(0)" ::: "memory");
        __builtin_amdgcn_s_barrier();
        __builtin_amdgcn_sched_barrier(0);
        if (ks + 2 < 16) stage((ks + 2) % 3, (ks + 2) << 5);
        bf16x8 af[4], bfr[4];
#pragma unroll
        for (int i = 0; i < 4; i++)
            af[i] = *reinterpret_cast<const bf16x8*>(&pool[cur * 4096 + (wr * 64 + i * 16 + lr) * 32 + colA]);
#pragma unroll
        for (int i = 0; i < 4; i++)
            bfr[i] = *reinterpret_cast<const bf16x8*>(&pool[12288 + cur * 4096 + (wc * 64 + i * 16 + lr) * 32 + colA]);
        __builtin_amdgcn_s_setprio(1);
#pragma unroll
        for (int mi = 0; mi < 4; mi++)
#pragma unroll
            for (int ni = 0; ni < 4; ni++)
                acc[mi][ni] = __builtin_amdgcn_mfma_f32_16x16x32_bf16(af[mi], bfr[ni], acc[mi][ni], 0, 0, 0);
        __builtin_amdgcn_s_setprio(0);
        cur = (cur + 1) % 3;
    }

    if (bx < 8) {
#pragma unroll
        for (int mi = 0; mi < 4; mi++) {
#pragma unroll
            for (int ni = 0; ni < 4; ni++) {
#pragma unroll
                for (int r = 0; r < 4; r++) {
                    const int row = m0 + wr * 64 + mi * 16 + lh * 4 + r;
                    const int col = n0 + wc * 64 + ni * 16 + lr;
                    const float v = acc[mi][ni][r];
                    const int part_ = col >> 9, hh = (col >> 6) & 7, d = col & 63;
                    const int b = row >> 11, n = row & 2047;
                    const size_t bh = (size_t)(b * 8 + hh);
                    if (part_ == 0)
                        qbuf[(bh * 2048 + n) * 64 + d] = f2bfu(v * 0.1803368801111244f);
                    else
                        kbuf[(bh * 2048 + n) * 64 + d] = f2bfu(v);
                }
            }
        }
    } else {
        asm volatile("s_waitcnt lgkmcnt(0)" ::: "memory");
        __builtin_amdgcn_s_barrier();
        __builtin_amdgcn_sched_barrier(0);
#pragma unroll
        for (int mi = 0; mi < 4; mi++) {
#pragma unroll
            for (int ni = 0; ni < 4; ni++) {
                const int cgrel = wc * 64 + ni * 16 + lr;
                const int nr0 = wr * 64 + mi * 16 + lh * 4;
                unsigned int w0 = (unsigned int)f2bfu(acc[mi][ni][0]) | ((unsigned int)f2bfu(acc[mi][ni][1]) << 16);
                unsigned int w1 = (unsigned int)f2bfu(acc[mi][ni][2]) | ((unsigned int)f2bfu(acc[mi][ni][3]) << 16);
                uint2 pk2; pk2.x = w0; pk2.y = w1;
                *reinterpret_cast<uint2*>(&pool[cgrel * 136 + nr0]) = pk2;
            }
        }
        asm volatile("s_waitcnt lgkmcnt(0)" ::: "memory");
        __builtin_amdgcn_s_barrier();
        __builtin_amdgcn_sched_barrier(0);
        const int cg = tid >> 1, half = tid & 1;
        const int b = by >> 4;
        const int nbase = (by & 15) * 128;
        const int cg0 = n0 - 1024;
        unsigned short* dstp = vtb + ((size_t)(b * 512 + cg0 + cg)) * 2048 + nbase + half * 64;
#pragma unroll
        for (int c = 0; c < 8; c++) {
            uint4 vv = *reinterpret_cast<const uint4*>(&pool[cg * 136 + half * 64 + c * 8]);
            *reinterpret_cast<uint4*>(dstp + c * 8) = vv;
        }
    }
}

// ---------------- GroupNorm apply (in place), stats finish folded in [R9-verified] ------
__global__ __launch_bounds__(256) void gn_apply(unsigned short* __restrict__ c1,
                                                unsigned short* __restrict__ c2,
                                                const float* __restrict__ part,
                                                const float* __restrict__ g1, const float* __restrict__ b1,
                                                const float* __restrict__ g2, const float* __restrict__ b2) {
    __shared__ float sst[2][32][2];
    const int tid = threadIdx.x;
    if (tid < 64) {
        const int z = tid >> 5, bg = tid & 31;
        const float S = part[(z * 32 + bg) * 2 + 0];
        const float Q = part[(z * 32 + bg) * 2 + 1];
        const float inv = 1.0f / 131072.0f;
        const float m = S * inv;
        const float v = fmaxf(Q * inv - m * m, 0.f);
        sst[z][bg][0] = m;
        sst[z][bg][1] = rsqrtf(v + 1e-5f);
    }
    __syncthreads();
    int i = blockIdx.x * 256 + tid;
    const int stride = gridDim.x * 256;
    for (; i < 524288; i += stride) {
        const size_t e = (size_t)i * 8;
        const int b = (int)(e >> 20);
        const int o = (int)(e & 511);
        const int g = o >> 6;
        const int bg = (b << 3) + g;
        const float m1 = sst[0][bg][0], r1 = sst[0][bg][1];
        const float m2 = sst[1][bg][0], r2 = sst[1][bg][1];
        uint4 v1 = *reinterpret_cast<const uint4*>(c1 + e);
        uint4 v2 = *reinterpret_cast<const uint4*>(c2 + e);
        unsigned int a1[4] = {v1.x, v1.y, v1.z, v1.w};
        unsigned int a2[4] = {v2.x, v2.y, v2.z, v2.w};
        unsigned int o1[4], o2[4];
#pragma unroll
        for (int j = 0; j < 4; j++) {
            const int oo = o + j * 2;
            float x0 = (bfu2f(a1[j] & 0xffffu) - m1) * r1 * g1[oo] + b1[oo];
            float x1 = (bfu2f(a1[j] >> 16) - m1) * r1 * g1[oo + 1] + b1[oo + 1];
            o1[j] = (unsigned int)f2bfu(x0) | ((unsigned int)f2bfu(x1) << 16);
            float y0 = (bfu2f(a2[j] & 0xffffu) - m2) * r2 * g2[oo] + b2[oo];
            float y1 = (bfu2f(a2[j] >> 16) - m2) * r2 * g2[oo + 1] + b2[oo + 1];
            o2[j] = (unsigned int)f2bfu(y0) | ((unsigned int)f2bfu(y1) << 16);
        }
        uint4 w1; w1.x = o1[0]; w1.y = o1[1]; w1.z = o1[2]; w1.w = o1[3];
        uint4 w2; w2.x = o2[0]; w2.y = o2[1]; w2.z = o2[2]; w2.w = o2[3];
        *reinterpret_cast<uint4*>(c1 + e) = w1;
        *reinterpret_cast<uint4*>(c2 + e) = w2;
    }
}

// ---------------- fused flash attention, 8-wave blocks, KVBLK=128 [R14-verified] --------
__global__ __launch_bounds__(512, 4) void attn_fused(
    const unsigned short* __restrict__ qb, const unsigned short* __restrict__ kb,
    const unsigned short* __restrict__ vT, const unsigned short* __restrict__ pea,
    unsigned short* __restrict__ hbuf) {
    __shared__ unsigned short Ks[2][128 * 64];
    __shared__ unsigned short Vs[2][64 * 128];
    __shared__ unsigned short Pl[8][16 * 64];
    const int tid = threadIdx.x, l = tid & 63, w = tid >> 6;
    const int lr = l & 15, lh = l >> 4;
    const int bid = blockIdx.x;
    const int h = bid >> 6, rst = bid & 63, nt = rst & 15, b = rst >> 4;
    const size_t bh = (size_t)(b * 8 + h);
    const unsigned short* qp = qb + bh * 2048 * 64;
    const unsigned short* kp = kb + bh * 2048 * 64;
    const unsigned short* vp = vT + bh * 64 * 2048;
    const unsigned short* pep = pea + (size_t)b * 2048 * 2048;   // [q][k] orientation
    const int qrow = nt * 128 + 16 * w + lr;                     // this lane's q-row

    bf16x8 qf[2];
    qf[0] = *reinterpret_cast<const bf16x8*>(qp + (size_t)qrow * 64 + lh * 8);
    qf[1] = *reinterpret_cast<const bf16x8*>(qp + (size_t)qrow * 64 + 32 + lh * 8);

    const int swz = (lr & 7) << 4;                       // byte XOR
    const int colK0 = ((16 * lh) ^ swz) >> 1;            // Ks row stride 64 shorts
    const int colK1 = ((64 + 16 * lh) ^ swz) >> 1;
    int colV[4];                                          // Vs row stride 128 shorts
#pragma unroll
    for (int c = 0; c < 4; c++) colV[c] = ((64 * c + 16 * lh) ^ swz) >> 1;

    const unsigned short* perp = pep + (size_t)qrow * 2048;
    uint2 peR[8];
#pragma unroll
    for (int mf = 0; mf < 8; mf++)
        peR[mf] = *reinterpret_cast<const uint2*>(perp + 16 * mf + 4 * lh);

    f32x4 oacc[4] = {};
    float mrun = -1e30f, lrun = 0.f;

    auto stage_kv = [&](int bufi, int m0) {
#pragma unroll
        for (int i = 0; i < 2; i++) {
            const int kc = w * 128 + i * 64 + l;          // K chunk id
            const int krow = kc >> 3, kslot = kc & 7;
            const int kcs = (kslot ^ (krow & 7)) * 8;
            __builtin_amdgcn_global_load_lds(
                (const __attribute__((address_space(1))) void*)(kp + (size_t)(m0 + krow) * 64 + kcs),
                (__attribute__((address_space(3))) void*)&Ks[bufi][(w * 128 + i * 64) * 8], 16, 0, 0);
            const int vrow = kc >> 4, vslot = kc & 15;
            const int vcs = (vslot ^ (vrow & 7)) * 8;
            __builtin_amdgcn_global_load_lds(
                (const __attribute__((address_space(1))) void*)(vp + (size_t)vrow * 2048 + m0 + vcs),
                (__attribute__((address_space(3))) void*)&Vs[bufi][(w * 128 + i * 64) * 8], 16, 0, 0);
        }
    };

    stage_kv(0, 0);
    asm volatile("s_waitcnt vmcnt(0)" ::: "memory");
    __builtin_amdgcn_s_barrier();
    __builtin_amdgcn_sched_barrier(0);

    for (int mt = 0; mt < 16; mt++) {
        const int cur = mt & 1;
        if (mt + 1 < 16) stage_kv(cur ^ 1, (mt + 1) * 128);
        const unsigned short* Kb = Ks[cur];
        const unsigned short* Vb = Vs[cur];

        f32x4 st[8];
        __builtin_amdgcn_s_setprio(1);
#pragma unroll
        for (int mf = 0; mf < 8; mf++) {
            f32x4 z = {};
            bf16x8 kf0 = *reinterpret_cast<const bf16x8*>(&Kb[(mf * 16 + lr) * 64 + colK0]);
            bf16x8 kf1 = *reinterpret_cast<const bf16x8*>(&Kb[(mf * 16 + lr) * 64 + colK1]);
            z = __builtin_amdgcn_mfma_f32_16x16x32_bf16(kf0, qf[0], z, 0, 0, 0);
            st[mf] = __builtin_amdgcn_mfma_f32_16x16x32_bf16(kf1, qf[1], z, 0, 0, 0);
        }
        __builtin_amdgcn_s_setprio(0);

        float p[8][4];
#pragma unroll
        for (int mf = 0; mf < 8; mf++) {
            p[mf][0] = st[mf][0] * bfu2f(peR[mf].x & 0xffffu);
            p[mf][1] = st[mf][1] * bfu2f(peR[mf].x >> 16);
            p[mf][2] = st[mf][2] * bfu2f(peR[mf].y & 0xffffu);
            p[mf][3] = st[mf][3] * bfu2f(peR[mf].y >> 16);
        }
        uint2 peN[8];
        if (mt + 1 < 16) {
            const unsigned short* pn = perp + (mt + 1) * 128;
#pragma unroll
            for (int mf = 0; mf < 8; mf++)
                peN[mf] = *reinterpret_cast<const uint2*>(pn + 16 * mf + 4 * lh);
        }
        float pm = fmaxf(p[0][0], p[0][1]);
        pm = fmaxf(fmaxf(pm, p[0][2]), p[0][3]);
#pragma unroll
        for (int mf = 1; mf < 8; mf++) {
            pm = fmaxf(fmaxf(pm, p[mf][0]), p[mf][1]);
            pm = fmaxf(fmaxf(pm, p[mf][2]), p[mf][3]);
        }
        pm = fmaxf(pm, __shfl_xor(pm, 16));
        pm = fmaxf(pm, __shfl_xor(pm, 32));
        if (__any(pm > mrun + 11.5416f)) {
            const float mnew = fmaxf(mrun, pm);
            const float fac = __builtin_amdgcn_exp2f(mrun - mnew);
            lrun *= fac;
#pragma unroll
            for (int df = 0; df < 4; df++)
#pragma unroll
                for (int r = 0; r < 4; r++) oacc[df][r] *= fac;
            mrun = mnew;
        }
        float ss = 0.f;
        unsigned int pk[16];
#pragma unroll
        for (int mf = 0; mf < 8; mf++) {
#pragma unroll
            for (int t = 0; t < 2; t++) {
                const float a = __builtin_amdgcn_exp2f(p[mf][2 * t] - mrun);
                const float c = __builtin_amdgcn_exp2f(p[mf][2 * t + 1] - mrun);
                unsigned int pkv;
                asm("v_cvt_pk_bf16_f32 %0, %1, %2" : "=v"(pkv) : "v"(a), "v"(c));
                pk[mf * 2 + t] = pkv;
                ss += a + c;
            }
        }
        ss += __shfl_xor(ss, 16);
        ss += __shfl_xor(ss, 32);
        lrun += ss;
        unsigned short* PlW = Pl[w];
        const int plswz = (lr & 7) << 4;               // byte XOR within 128B row
#pragma unroll
        for (int kh = 0; kh < 2; kh++) {
#pragma unroll
            for (int mq = 0; mq < 4; mq++)
#pragma unroll
                for (int t = 0; t < 2; t++) {
                    const int cb = (mq * 32 + lh * 8 + 4 * t) ^ plswz;
                    *reinterpret_cast<unsigned int*>(&PlW[lr * 64 + (cb >> 1)]) = pk[(kh * 4 + mq) * 2 + t];
                }
            bf16x8 pb0 = *reinterpret_cast<const bf16x8*>(&PlW[lr * 64 + (((lh * 16) ^ plswz) >> 1)]);
            bf16x8 pb1 = *reinterpret_cast<const bf16x8*>(&PlW[lr * 64 + (((64 + lh * 16) ^ plswz) >> 1)]);
            __builtin_amdgcn_s_setprio(1);
#pragma unroll
            for (int df = 0; df < 4; df++) {
                bf16x8 vf0 = *reinterpret_cast<const bf16x8*>(&Vb[(df * 16 + lr) * 128 + colV[kh * 2]]);
                bf16x8 vf1 = *reinterpret_cast<const bf16x8*>(&Vb[(df * 16 + lr) * 128 + colV[kh * 2 + 1]]);
                oacc[df] = __builtin_amdgcn_mfma_f32_16x16x32_bf16(vf0, pb0, oacc[df], 0, 0, 0);
                oacc[df] = __builtin_amdgcn_mfma_f32_16x16x32_bf16(vf1, pb1, oacc[df], 0, 0, 0);
            }
            __builtin_amdgcn_s_setprio(0);
        }
        if (mt + 1 < 16) {
            asm volatile("s_waitcnt vmcnt(0) lgkmcnt(0)" ::: "memory");
            __builtin_amdgcn_s_barrier();
            __builtin_amdgcn_sched_barrier(0);
#pragma unroll
            for (int mf = 0; mf < 8; mf++) peR[mf] = peN[mf];
        }
    }
    const float inv = 1.0f / lrun;
    const size_t base = ((size_t)b * 2048 + qrow) * 512 + h * 64;
#pragma unroll
    for (int df = 0; df < 4; df++) {
#pragma unroll
        for (int t = 0; t < 2; t++) {
            const unsigned int ua = f2bfu(oacc[df][2 * t] * inv);
            const unsigned int uc = f2bfu(oacc[df][2 * t + 1] * inv);
            *reinterpret_cast<unsigned int*>(&hbuf[base + 16 * df + 4 * lh + 2 * t]) = ua | (uc << 16);
        }
    }
}

extern "C" void kernel_launch(void* const* d_in, const int* in_sizes, int n_in,
                              void* d_out, int out_size, void* d_ws, size_t ws_size,
                              hipStream_t stream) {
    const float* x       = (const float*)d_in[0];
    const float* pe      = (const float*)d_in[1];
    const float* qkv_w   = (const float*)d_in[2];
    const float* proj_w  = (const float*)d_in[3];
    const float* proj_b  = (const float*)d_in[4];
    const float* conv1_w = (const float*)d_in[5];
    const float* conv1_b = (const float*)d_in[6];
    const float* gn1_g   = (const float*)d_in[7];
    const float* gn1_b   = (const float*)d_in[8];
    const float* conv2_w = (const float*)d_in[9];
    const float* conv2_b = (const float*)d_in[10];
    const float* gn2_g   = (const float*)d_in[11];
    const float* gn2_b   = (const float*)d_in[12];
    float* out = (float*)d_out;

    char* ws = (char*)d_ws;
    size_t off = 0;
    auto alloc = [&](size_t bytes) -> void* {
        void* p = ws + off;
        off += (bytes + 255) & ~(size_t)255;
        return p;
    };
    unsigned short* xb     = (unsigned short*)alloc(8388608);   // x bf16 [B*N, C]
    unsigned short* peb    = (unsigned short*)alloc(8388608);   // pe bf16
    unsigned short* qkvwb  = (unsigned short*)alloc(1572864);   // qkv_w bf16 [1536,512]
    unsigned short* projwb = (unsigned short*)alloc(524288);
    unsigned short* w1b    = (unsigned short*)alloc(524288);    // w1b/w2b contiguous (sB=262144)
    unsigned short* w2b    = (unsigned short*)alloc(524288);
    unsigned short* c1b    = (unsigned short*)alloc(8388608);   // c1b/c2b contiguous (sC=4194304)
    unsigned short* c2b    = (unsigned short*)alloc(8388608);
    unsigned short* qbuf   = (unsigned short*)alloc(8388608);   // [B,H,N,D] (q pre-scaled)
    unsigned short* kbuf   = (unsigned short*)alloc(8388608);
    unsigned short* vtb    = (unsigned short*)alloc(8388608);   // [B,H,D,N]
    unsigned short* peatt  = (unsigned short*)alloc(33554432);  // pe_attn [B,N(q),N(k)] bf16
    unsigned short* hbuf   = (unsigned short*)alloc(8388608);   // [B,N,C] bf16
    float* part            = (float*)alloc(512);                // GN stats [2][32][2]
    float* biasws          = (float*)alloc(4096);               // conv biases [2][512]

    dim3 blk(256);
    hipMemsetAsync(part, 0, 512, stream);
    cvt_all<<<2048, blk, 0, stream>>>(x, xb, pe, peb, qkv_w, qkvwb, proj_w, projwb,
                                      conv1_w, w1b, conv2_w, w2b, conv1_b, conv2_b, biasws);

    // conv1+conv2 in one launch (bz selects weights/bias/output); GN stats via atomics
    gemm_nt<0><<<dim3(512), blk, 0, stream>>>(peb, w1b, c1b, part, nullptr, biasws,
                                              512, 0, 262144, 4194304, 4, 64);
    gn_apply<<<1024, blk, 0, stream>>>(c1b, c2b, part, gn1_g, gn1_b, gn2_g, gn2_b);
    // qkv = x @ qkv_w.T -> q (x0.125*log2e), k [B,H,N,D]; vT [B,H,D,N] via LDS transpose
    gemm_qkv<<<dim3(768), blk, 0, stream>>>(xb, qkvwb, qbuf, kbuf, vtb);
    // pe_attn[b][n][m] = sigmoid(sum_k p1[n][k] p2[m][k]) — 256x128 tiles
    gemm_pe<<<dim3(512), blk, 0, stream>>>(c1b, c2b, peatt);
    attn_fused<<<dim3(512), dim3(512), 0, stream>>>(qbuf, kbuf, vtb, peatt, hbuf);
    // proj: out = h @ proj_w.T + proj_b (f32)
    gemm_nt<3><<<dim3(256), blk, 0, stream>>>(hbuf, projwb, out, nullptr, nullptr, proj_b,
                                              512, 0, 0, 0, 4, 64);
}

// Round 18
// 216.584 us; speedup vs baseline: 1.0105x; 1.0105x over previous
//
#include <hip/hip_runtime.h>
#include <hip/hip_bf16.h>

// Shapes (fixed): B=4, N=2048, C=512, H=8, D=64, GROUPS=8, C/G=64
typedef __attribute__((ext_vector_type(8))) short bf16x8;
typedef __attribute__((ext_vector_type(4))) float f32x4;

__device__ __forceinline__ float bfu2f(unsigned int u) {
    return __uint_as_float(u << 16);
}
__device__ __forceinline__ unsigned short f2bfu(float f) {
    unsigned int u = __float_as_uint(f);
    u += 0x7fffu + ((u >> 16) & 1u);   // RNE
    return (unsigned short)(u >> 16);
}

// ---------------- all fp32->bf16 conversions + bias gather, one launch ----------------
__global__ __launch_bounds__(256) void cvt_all(
    const float* __restrict__ x, unsigned short* __restrict__ xb,
    const float* __restrict__ pe, unsigned short* __restrict__ peb,
    const float* __restrict__ w0, unsigned short* __restrict__ d0,
    const float* __restrict__ w1, unsigned short* __restrict__ d1,
    const float* __restrict__ w2, unsigned short* __restrict__ d2,
    const float* __restrict__ w3, unsigned short* __restrict__ d3,
    const float* __restrict__ c1bias, const float* __restrict__ c2bias,
    float* __restrict__ biasws) {
    const int tid = threadIdx.x;
    if (blockIdx.x == 0) {
        if (tid < 128) ((float4*)biasws)[tid] = ((const float4*)c1bias)[tid];
        else ((float4*)biasws)[tid] = ((const float4*)c2bias)[tid - 128];
    }
    int i = blockIdx.x * 256 + tid;
    const int stride = gridDim.x * 256;
    for (; i < 1441792; i += stride) {
        if (i < 1048576) {
            float4 v = reinterpret_cast<const float4*>(x)[i];
            ushort4 o;
            o.x = f2bfu(v.x); o.y = f2bfu(v.y); o.z = f2bfu(v.z); o.w = f2bfu(v.w);
            reinterpret_cast<ushort4*>(xb)[i] = o;
            float4 u = reinterpret_cast<const float4*>(pe)[i];
            ushort4 p;
            p.x = f2bfu(u.x); p.y = f2bfu(u.y); p.z = f2bfu(u.z); p.w = f2bfu(u.w);
            reinterpret_cast<ushort4*>(peb)[i] = p;
        } else {
            int j = i - 1048576;
            const float* s; unsigned short* d;
            if (j < 196608)      { s = w0; d = d0; }
            else if (j < 262144) { s = w1; d = d1; j -= 196608; }
            else if (j < 327680) { s = w2; d = d2; j -= 262144; }
            else                 { s = w3; d = d3; j -= 327680; }
            float4 v = reinterpret_cast<const float4*>(s)[j];
            ushort4 o;
            o.x = f2bfu(v.x); o.y = f2bfu(v.y); o.z = f2bfu(v.z); o.w = f2bfu(v.w);
            reinterpret_cast<ushort4*>(d)[j] = o;
        }
    }
}

// ---------------- generic NT GEMM, 3-buffer rotation + counted vmcnt [R15-verified] -----
// EPI: 0 = conv pair (bf16 out, +bias, GN stats atomics via C1),
//      2 = sigmoid bf16 (ld2048, batched), 3 = proj (f32 out, +bias)
template <int EPI>
__global__ __launch_bounds__(256) void gemm_nt(
    const unsigned short* __restrict__ A, const unsigned short* __restrict__ B,
    void* __restrict__ C0, void* __restrict__ C1, void* __restrict__ C2,
    const float* __restrict__ bias, int K, long sA, long sB, long sC,
    int nx, int ny) {
    __shared__ unsigned short As[3][128 * 32];
    __shared__ unsigned short Bs[3][128 * 32];
    int lin = blockIdx.x;
    const int qsw = gridDim.x >> 3;
    lin = (lin & 7) * qsw + (lin >> 3);          // bijective XCD swizzle (grid % 8 == 0)
    const int bx = lin % nx;
    const int t2 = lin / nx;
    const int by = t2 % ny;
    const int bz = t2 / ny;
    const int tid = threadIdx.x;
    const int l = tid & 63, w = tid >> 6;
    const int wr = w >> 1, wc = w & 1, lr = l & 15, lh = l >> 4;
    const int m0 = by * 128, n0 = bx * 128;
    A += (size_t)bz * sA;
    B += (size_t)bz * sB;
    f32x4 acc[4][4] = {};

    const int srow = l >> 2, sslot = l & 3;
    auto stage = [&](int bufi, int k0) {
#pragma unroll
        for (int i = 0; i < 2; i++) {
            const int row = w * 32 + i * 16 + srow;
            const int cs = (sslot ^ (row & 3)) * 8;
            const int ldsoff = (w * 32 + i * 16) * 32;
            __builtin_amdgcn_global_load_lds(
                (const __attribute__((address_space(1))) void*)(A + (size_t)(m0 + row) * K + k0 + cs),
                (__attribute__((address_space(3))) void*)&As[bufi][ldsoff], 16, 0, 0);
            __builtin_amdgcn_global_load_lds(
                (const __attribute__((address_space(1))) void*)(B + (size_t)(n0 + row) * K + k0 + cs),
                (__attribute__((address_space(3))) void*)&Bs[bufi][ldsoff], 16, 0, 0);
        }
    };

    const int nks = K >> 5;
    stage(0, 0);
    stage(1, 32);

    const int colA = (lh ^ (lr & 3)) << 3;
    int cur = 0;
    for (int ks = 0; ks < nks; ks++) {
        if (ks == nks - 1)
            asm volatile("s_waitcnt vmcnt(0) lgkmcnt(0)" ::: "memory");
        else
            asm volatile("s_waitcnt vmcnt(4) lgkmcnt(0)" ::: "memory");
        __builtin_amdgcn_s_barrier();
        __builtin_amdgcn_sched_barrier(0);
        if (ks + 2 < nks) stage((ks + 2) % 3, (ks + 2) << 5);
        bf16x8 af[4], bfr[4];
#pragma unroll
        for (int i = 0; i < 4; i++)
            af[i] = *reinterpret_cast<const bf16x8*>(&As[cur][(wr * 64 + i * 16 + lr) * 32 + colA]);
#pragma unroll
        for (int i = 0; i < 4; i++)
            bfr[i] = *reinterpret_cast<const bf16x8*>(&Bs[cur][(wc * 64 + i * 16 + lr) * 32 + colA]);
        __builtin_amdgcn_s_setprio(1);
#pragma unroll
        for (int mi = 0; mi < 4; mi++)
#pragma unroll
            for (int ni = 0; ni < 4; ni++)
                acc[mi][ni] = __builtin_amdgcn_mfma_f32_16x16x32_bf16(af[mi], bfr[ni], acc[mi][ni], 0, 0, 0);
        __builtin_amdgcn_s_setprio(0);
        cur = (cur + 1) % 3;
    }

    float sgn = 0.f, qgn = 0.f;   // fused GN partial stats (EPI==0)
#pragma unroll
    for (int mi = 0; mi < 4; mi++) {
#pragma unroll
        for (int ni = 0; ni < 4; ni++) {
#pragma unroll
            for (int r = 0; r < 4; r++) {
                const int row = m0 + wr * 64 + mi * 16 + lh * 4 + r;
                const int col = n0 + wc * 64 + ni * 16 + lr;
                float v = acc[mi][ni][r];
                if constexpr (EPI == 0) {
                    v += bias[bz * 512 + col];
                    sgn += v; qgn += v * v;
                    ((unsigned short*)C0)[(size_t)bz * sC + (size_t)row * 512 + col] = f2bfu(v);
                } else if constexpr (EPI == 2) {
                    const float sg = 1.0f / (1.0f + __expf(-v));
                    ((unsigned short*)C0)[(size_t)bz * sC + (size_t)row * 2048 + col] = f2bfu(sg);
                } else {
                    ((float*)C0)[(size_t)row * 512 + col] = v + bias[col];
                }
            }
        }
    }
    if constexpr (EPI == 0) {
        // wave holds one (b,g): b = by>>4, g = bx*2+wc
#pragma unroll
        for (int s = 1; s < 64; s <<= 1) {
            sgn += __shfl_xor(sgn, s);
            qgn += __shfl_xor(qgn, s);
        }
        if (l == 0) {
            const int bg = ((by >> 4) << 3) + bx * 2 + wc;
            float* part = (float*)C1;
            atomicAdd(&part[(bz * 32 + bg) * 2 + 0], sgn);
            atomicAdd(&part[(bz * 32 + bg) * 2 + 1], qgn);
        }
    }
}

// ---------------- qkv GEMM [R16-verified] ----------------
__global__ __launch_bounds__(256) void gemm_qkv(
    const unsigned short* __restrict__ A, const unsigned short* __restrict__ B,
    unsigned short* __restrict__ qbuf, unsigned short* __restrict__ kbuf,
    unsigned short* __restrict__ vtb) {
    __shared__ unsigned short pool[24576];       // As = pool[0..12287], Bs = pool[12288..]
    int lin = blockIdx.x;
    lin = (lin & 7) * 96 + (lin >> 3);           // 768 = 8*96
    const int bx = lin % 12;
    const int by = lin / 12;
    const int tid = threadIdx.x;
    const int l = tid & 63, w = tid >> 6;
    const int wr = w >> 1, wc = w & 1, lr = l & 15, lh = l >> 4;
    const int m0 = by * 128, n0 = bx * 128;
    f32x4 acc[4][4] = {};

    const int srow = l >> 2, sslot = l & 3;
    auto stage = [&](int bufi, int k0) {
#pragma unroll
        for (int i = 0; i < 2; i++) {
            const int row = w * 32 + i * 16 + srow;
            const int cs = (sslot ^ (row & 3)) * 8;
            const int ldsoff = bufi * 4096 + (w * 32 + i * 16) * 32;
            __builtin_amdgcn_global_load_lds(
                (const __attribute__((address_space(1))) void*)(A + (size_t)(m0 + row) * 512 + k0 + cs),
                (__attribute__((address_space(3))) void*)&pool[ldsoff], 16, 0, 0);
            __builtin_amdgcn_global_load_lds(
                (const __attribute__((address_space(1))) void*)(B + (size_t)(n0 + row) * 512 + k0 + cs),
                (__attribute__((address_space(3))) void*)&pool[12288 + ldsoff], 16, 0, 0);
        }
    };

    stage(0, 0);
    stage(1, 32);

    const int colA = (lh ^ (lr & 3)) << 3;
    int cur = 0;
    for (int ks = 0; ks < 16; ks++) {
        if (ks == 15)
            asm volatile("s_waitcnt vmcnt(0) lgkmcnt(0)" ::: "memory");
        else
            asm volatile("s_waitcnt vmcnt(4) lgkmcnt(0)" ::: "memory");
        __builtin_amdgcn_s_barrier();
        __builtin_amdgcn_sched_barrier(0);
        if (ks + 2 < 16) stage((ks + 2) % 3, (ks + 2) << 5);
        bf16x8 af[4], bfr[4];
#pragma unroll
        for (int i = 0; i < 4; i++)
            af[i] = *reinterpret_cast<const bf16x8*>(&pool[cur * 4096 + (wr * 64 + i * 16 + lr) * 32 + colA]);
#pragma unroll
        for (int i = 0; i < 4; i++)
            bfr[i] = *reinterpret_cast<const bf16x8*>(&pool[12288 + cur * 4096 + (wc * 64 + i * 16 + lr) * 32 + colA]);
        __builtin_amdgcn_s_setprio(1);
#pragma unroll
        for (int mi = 0; mi < 4; mi++)
#pragma unroll
            for (int ni = 0; ni < 4; ni++)
                acc[mi][ni] = __builtin_amdgcn_mfma_f32_16x16x32_bf16(af[mi], bfr[ni], acc[mi][ni], 0, 0, 0);
        __builtin_amdgcn_s_setprio(0);
        cur = (cur + 1) % 3;
    }

    if (bx < 8) {
#pragma unroll
        for (int mi = 0; mi < 4; mi++) {
#pragma unroll
            for (int ni = 0; ni < 4; ni++) {
#pragma unroll
                for (int r = 0; r < 4; r++) {
                    const int row = m0 + wr * 64 + mi * 16 + lh * 4 + r;
                    const int col = n0 + wc * 64 + ni * 16 + lr;
                    const float v = acc[mi][ni][r];
                    const int part_ = col >> 9, hh = (col >> 6) & 7, d = col & 63;
                    const int b = row >> 11, n = row & 2047;
                    const size_t bh = (size_t)(b * 8 + hh);
                    if (part_ == 0)
                        qbuf[(bh * 2048 + n) * 64 + d] = f2bfu(v * 0.1803368801111244f);
                    else
                        kbuf[(bh * 2048 + n) * 64 + d] = f2bfu(v);
                }
            }
        }
    } else {
        asm volatile("s_waitcnt lgkmcnt(0)" ::: "memory");
        __builtin_amdgcn_s_barrier();
        __builtin_amdgcn_sched_barrier(0);
#pragma unroll
        for (int mi = 0; mi < 4; mi++) {
#pragma unroll
            for (int ni = 0; ni < 4; ni++) {
                const int cgrel = wc * 64 + ni * 16 + lr;
                const int nr0 = wr * 64 + mi * 16 + lh * 4;
                unsigned int w0 = (unsigned int)f2bfu(acc[mi][ni][0]) | ((unsigned int)f2bfu(acc[mi][ni][1]) << 16);
                unsigned int w1 = (unsigned int)f2bfu(acc[mi][ni][2]) | ((unsigned int)f2bfu(acc[mi][ni][3]) << 16);
                uint2 pk2; pk2.x = w0; pk2.y = w1;
                *reinterpret_cast<uint2*>(&pool[cgrel * 136 + nr0]) = pk2;
            }
        }
        asm volatile("s_waitcnt lgkmcnt(0)" ::: "memory");
        __builtin_amdgcn_s_barrier();
        __builtin_amdgcn_sched_barrier(0);
        const int cg = tid >> 1, half = tid & 1;
        const int b = by >> 4;
        const int nbase = (by & 15) * 128;
        const int cg0 = n0 - 1024;
        unsigned short* dstp = vtb + ((size_t)(b * 512 + cg0 + cg)) * 2048 + nbase + half * 64;
#pragma unroll
        for (int c = 0; c < 8; c++) {
            uint4 vv = *reinterpret_cast<const uint4*>(&pool[cg * 136 + half * 64 + c * 8]);
            *reinterpret_cast<uint4*>(dstp + c * 8) = vv;
        }
    }
}

// ---------------- GroupNorm apply (in place), stats finish folded in [R9-verified] ------
__global__ __launch_bounds__(256) void gn_apply(unsigned short* __restrict__ c1,
                                                unsigned short* __restrict__ c2,
                                                const float* __restrict__ part,
                                                const float* __restrict__ g1, const float* __restrict__ b1,
                                                const float* __restrict__ g2, const float* __restrict__ b2) {
    __shared__ float sst[2][32][2];
    const int tid = threadIdx.x;
    if (tid < 64) {
        const int z = tid >> 5, bg = tid & 31;
        const float S = part[(z * 32 + bg) * 2 + 0];
        const float Q = part[(z * 32 + bg) * 2 + 1];
        const float inv = 1.0f / 131072.0f;
        const float m = S * inv;
        const float v = fmaxf(Q * inv - m * m, 0.f);
        sst[z][bg][0] = m;
        sst[z][bg][1] = rsqrtf(v + 1e-5f);
    }
    __syncthreads();
    int i = blockIdx.x * 256 + tid;
    const int stride = gridDim.x * 256;
    for (; i < 524288; i += stride) {
        const size_t e = (size_t)i * 8;
        const int b = (int)(e >> 20);
        const int o = (int)(e & 511);
        const int g = o >> 6;
        const int bg = (b << 3) + g;
        const float m1 = sst[0][bg][0], r1 = sst[0][bg][1];
        const float m2 = sst[1][bg][0], r2 = sst[1][bg][1];
        uint4 v1 = *reinterpret_cast<const uint4*>(c1 + e);
        uint4 v2 = *reinterpret_cast<const uint4*>(c2 + e);
        unsigned int a1[4] = {v1.x, v1.y, v1.z, v1.w};
        unsigned int a2[4] = {v2.x, v2.y, v2.z, v2.w};
        unsigned int o1[4], o2[4];
#pragma unroll
        for (int j = 0; j < 4; j++) {
            const int oo = o + j * 2;
            float x0 = (bfu2f(a1[j] & 0xffffu) - m1) * r1 * g1[oo] + b1[oo];
            float x1 = (bfu2f(a1[j] >> 16) - m1) * r1 * g1[oo + 1] + b1[oo + 1];
            o1[j] = (unsigned int)f2bfu(x0) | ((unsigned int)f2bfu(x1) << 16);
            float y0 = (bfu2f(a2[j] & 0xffffu) - m2) * r2 * g2[oo] + b2[oo];
            float y1 = (bfu2f(a2[j] >> 16) - m2) * r2 * g2[oo + 1] + b2[oo + 1];
            o2[j] = (unsigned int)f2bfu(y0) | ((unsigned int)f2bfu(y1) << 16);
        }
        uint4 w1; w1.x = o1[0]; w1.y = o1[1]; w1.z = o1[2]; w1.w = o1[3];
        uint4 w2; w2.x = o2[0]; w2.y = o2[1]; w2.z = o2[2]; w2.w = o2[3];
        *reinterpret_cast<uint4*>(c1 + e) = w1;
        *reinterpret_cast<uint4*>(c2 + e) = w2;
    }
}

// ---------------- fused flash attention, 8-wave blocks, KVBLK=128 [R14-verified] --------
__global__ __launch_bounds__(512, 4) void attn_fused(
    const unsigned short* __restrict__ qb, const unsigned short* __restrict__ kb,
    const unsigned short* __restrict__ vT, const unsigned short* __restrict__ pea,
    unsigned short* __restrict__ hbuf) {
    __shared__ unsigned short Ks[2][128 * 64];
    __shared__ unsigned short Vs[2][64 * 128];
    __shared__ unsigned short Pl[8][16 * 64];
    const int tid = threadIdx.x, l = tid & 63, w = tid >> 6;
    const int lr = l & 15, lh = l >> 4;
    const int bid = blockIdx.x;
    const int h = bid >> 6, rst = bid & 63, nt = rst & 15, b = rst >> 4;
    const size_t bh = (size_t)(b * 8 + h);
    const unsigned short* qp = qb + bh * 2048 * 64;
    const unsigned short* kp = kb + bh * 2048 * 64;
    const unsigned short* vp = vT + bh * 64 * 2048;
    const unsigned short* pep = pea + (size_t)b * 2048 * 2048;   // [q][k] orientation
    const int qrow = nt * 128 + 16 * w + lr;                     // this lane's q-row

    bf16x8 qf[2];
    qf[0] = *reinterpret_cast<const bf16x8*>(qp + (size_t)qrow * 64 + lh * 8);
    qf[1] = *reinterpret_cast<const bf16x8*>(qp + (size_t)qrow * 64 + 32 + lh * 8);

    const int swz = (lr & 7) << 4;                       // byte XOR
    const int colK0 = ((16 * lh) ^ swz) >> 1;            // Ks row stride 64 shorts
    const int colK1 = ((64 + 16 * lh) ^ swz) >> 1;
    int colV[4];                                          // Vs row stride 128 shorts
#pragma unroll
    for (int c = 0; c < 4; c++) colV[c] = ((64 * c + 16 * lh) ^ swz) >> 1;

    const unsigned short* perp = pep + (size_t)qrow * 2048;
    uint2 peR[8];
#pragma unroll
    for (int mf = 0; mf < 8; mf++)
        peR[mf] = *reinterpret_cast<const uint2*>(perp + 16 * mf + 4 * lh);

    f32x4 oacc[4] = {};
    float mrun = -1e30f, lrun = 0.f;

    auto stage_kv = [&](int bufi, int m0) {
#pragma unroll
        for (int i = 0; i < 2; i++) {
            const int kc = w * 128 + i * 64 + l;          // K chunk id
            const int krow = kc >> 3, kslot = kc & 7;
            const int kcs = (kslot ^ (krow & 7)) * 8;
            __builtin_amdgcn_global_load_lds(
                (const __attribute__((address_space(1))) void*)(kp + (size_t)(m0 + krow) * 64 + kcs),
                (__attribute__((address_space(3))) void*)&Ks[bufi][(w * 128 + i * 64) * 8], 16, 0, 0);
            const int vrow = kc >> 4, vslot = kc & 15;
            const int vcs = (vslot ^ (vrow & 7)) * 8;
            __builtin_amdgcn_global_load_lds(
                (const __attribute__((address_space(1))) void*)(vp + (size_t)vrow * 2048 + m0 + vcs),
                (__attribute__((address_space(3))) void*)&Vs[bufi][(w * 128 + i * 64) * 8], 16, 0, 0);
        }
    };

    stage_kv(0, 0);
    asm volatile("s_waitcnt vmcnt(0)" ::: "memory");
    __builtin_amdgcn_s_barrier();
    __builtin_amdgcn_sched_barrier(0);

    for (int mt = 0; mt < 16; mt++) {
        const int cur = mt & 1;
        if (mt + 1 < 16) stage_kv(cur ^ 1, (mt + 1) * 128);
        const unsigned short* Kb = Ks[cur];
        const unsigned short* Vb = Vs[cur];

        f32x4 st[8];
        __builtin_amdgcn_s_setprio(1);
#pragma unroll
        for (int mf = 0; mf < 8; mf++) {
            f32x4 z = {};
            bf16x8 kf0 = *reinterpret_cast<const bf16x8*>(&Kb[(mf * 16 + lr) * 64 + colK0]);
            bf16x8 kf1 = *reinterpret_cast<const bf16x8*>(&Kb[(mf * 16 + lr) * 64 + colK1]);
            z = __builtin_amdgcn_mfma_f32_16x16x32_bf16(kf0, qf[0], z, 0, 0, 0);
            st[mf] = __builtin_amdgcn_mfma_f32_16x16x32_bf16(kf1, qf[1], z, 0, 0, 0);
        }
        __builtin_amdgcn_s_setprio(0);

        float p[8][4];
#pragma unroll
        for (int mf = 0; mf < 8; mf++) {
            p[mf][0] = st[mf][0] * bfu2f(peR[mf].x & 0xffffu);
            p[mf][1] = st[mf][1] * bfu2f(peR[mf].x >> 16);
            p[mf][2] = st[mf][2] * bfu2f(peR[mf].y & 0xffffu);
            p[mf][3] = st[mf][3] * bfu2f(peR[mf].y >> 16);
        }
        uint2 peN[8];
        if (mt + 1 < 16) {
            const unsigned short* pn = perp + (mt + 1) * 128;
#pragma unroll
            for (int mf = 0; mf < 8; mf++)
                peN[mf] = *reinterpret_cast<const uint2*>(pn + 16 * mf + 4 * lh);
        }
        float pm = fmaxf(p[0][0], p[0][1]);
        pm = fmaxf(fmaxf(pm, p[0][2]), p[0][3]);
#pragma unroll
        for (int mf = 1; mf < 8; mf++) {
            pm = fmaxf(fmaxf(pm, p[mf][0]), p[mf][1]);
            pm = fmaxf(fmaxf(pm, p[mf][2]), p[mf][3]);
        }
        pm = fmaxf(pm, __shfl_xor(pm, 16));
        pm = fmaxf(pm, __shfl_xor(pm, 32));
        if (__any(pm > mrun + 11.5416f)) {
            const float mnew = fmaxf(mrun, pm);
            const float fac = __builtin_amdgcn_exp2f(mrun - mnew);
            lrun *= fac;
#pragma unroll
            for (int df = 0; df < 4; df++)
#pragma unroll
                for (int r = 0; r < 4; r++) oacc[df][r] *= fac;
            mrun = mnew;
        }
        float ss = 0.f;
        unsigned int pk[16];
#pragma unroll
        for (int mf = 0; mf < 8; mf++) {
#pragma unroll
            for (int t = 0; t < 2; t++) {
                const float a = __builtin_amdgcn_exp2f(p[mf][2 * t] - mrun);
                const float c = __builtin_amdgcn_exp2f(p[mf][2 * t + 1] - mrun);
                unsigned int pkv;
                asm("v_cvt_pk_bf16_f32 %0, %1, %2" : "=v"(pkv) : "v"(a), "v"(c));
                pk[mf * 2 + t] = pkv;
                ss += a + c;
            }
        }
        ss += __shfl_xor(ss, 16);
        ss += __shfl_xor(ss, 32);
        lrun += ss;
        unsigned short* PlW = Pl[w];
        const int plswz = (lr & 7) << 4;               // byte XOR within 128B row
#pragma unroll
        for (int kh = 0; kh < 2; kh++) {
#pragma unroll
            for (int mq = 0; mq < 4; mq++)
#pragma unroll
                for (int t = 0; t < 2; t++) {
                    const int cb = (mq * 32 + lh * 8 + 4 * t) ^ plswz;
                    *reinterpret_cast<unsigned int*>(&PlW[lr * 64 + (cb >> 1)]) = pk[(kh * 4 + mq) * 2 + t];
                }
            bf16x8 pb0 = *reinterpret_cast<const bf16x8*>(&PlW[lr * 64 + (((lh * 16) ^ plswz) >> 1)]);
            bf16x8 pb1 = *reinterpret_cast<const bf16x8*>(&PlW[lr * 64 + (((64 + lh * 16) ^ plswz) >> 1)]);
            __builtin_amdgcn_s_setprio(1);
#pragma unroll
            for (int df = 0; df < 4; df++) {
                bf16x8 vf0 = *reinterpret_cast<const bf16x8*>(&Vb[(df * 16 + lr) * 128 + colV[kh * 2]]);
                bf16x8 vf1 = *reinterpret_cast<const bf16x8*>(&Vb[(df * 16 + lr) * 128 + colV[kh * 2 + 1]]);
                oacc[df] = __builtin_amdgcn_mfma_f32_16x16x32_bf16(vf0, pb0, oacc[df], 0, 0, 0);
                oacc[df] = __builtin_amdgcn_mfma_f32_16x16x32_bf16(vf1, pb1, oacc[df], 0, 0, 0);
            }
            __builtin_amdgcn_s_setprio(0);
        }
        if (mt + 1 < 16) {
            asm volatile("s_waitcnt vmcnt(0) lgkmcnt(0)" ::: "memory");
            __builtin_amdgcn_s_barrier();
            __builtin_amdgcn_sched_barrier(0);
#pragma unroll
            for (int mf = 0; mf < 8; mf++) peR[mf] = peN[mf];
        }
    }
    const float inv = 1.0f / lrun;
    const size_t base = ((size_t)b * 2048 + qrow) * 512 + h * 64;
#pragma unroll
    for (int df = 0; df < 4; df++) {
#pragma unroll
        for (int t = 0; t < 2; t++) {
            const unsigned int ua = f2bfu(oacc[df][2 * t] * inv);
            const unsigned int uc = f2bfu(oacc[df][2 * t + 1] * inv);
            *reinterpret_cast<unsigned int*>(&hbuf[base + 16 * df + 4 * lh + 2 * t]) = ua | (uc << 16);
        }
    }
}

extern "C" void kernel_launch(void* const* d_in, const int* in_sizes, int n_in,
                              void* d_out, int out_size, void* d_ws, size_t ws_size,
                              hipStream_t stream) {
    const float* x       = (const float*)d_in[0];
    const float* pe      = (const float*)d_in[1];
    const float* qkv_w   = (const float*)d_in[2];
    const float* proj_w  = (const float*)d_in[3];
    const float* proj_b  = (const float*)d_in[4];
    const float* conv1_w = (const float*)d_in[5];
    const float* conv1_b = (const float*)d_in[6];
    const float* gn1_g   = (const float*)d_in[7];
    const float* gn1_b   = (const float*)d_in[8];
    const float* conv2_w = (const float*)d_in[9];
    const float* conv2_b = (const float*)d_in[10];
    const float* gn2_g   = (const float*)d_in[11];
    const float* gn2_b   = (const float*)d_in[12];
    float* out = (float*)d_out;

    char* ws = (char*)d_ws;
    size_t off = 0;
    auto alloc = [&](size_t bytes) -> void* {
        void* p = ws + off;
        off += (bytes + 255) & ~(size_t)255;
        return p;
    };
    unsigned short* xb     = (unsigned short*)alloc(8388608);   // x bf16 [B*N, C]
    unsigned short* peb    = (unsigned short*)alloc(8388608);   // pe bf16
    unsigned short* qkvwb  = (unsigned short*)alloc(1572864);   // qkv_w bf16 [1536,512]
    unsigned short* projwb = (unsigned short*)alloc(524288);
    unsigned short* w1b    = (unsigned short*)alloc(524288);    // w1b/w2b contiguous (sB=262144)
    unsigned short* w2b    = (unsigned short*)alloc(524288);
    unsigned short* c1b    = (unsigned short*)alloc(8388608);   // c1b/c2b contiguous (sC=4194304)
    unsigned short* c2b    = (unsigned short*)alloc(8388608);
    unsigned short* qbuf   = (unsigned short*)alloc(8388608);   // [B,H,N,D] (q pre-scaled)
    unsigned short* kbuf   = (unsigned short*)alloc(8388608);
    unsigned short* vtb    = (unsigned short*)alloc(8388608);   // [B,H,D,N]
    unsigned short* peatt  = (unsigned short*)alloc(33554432);  // pe_attn [B,N(q),N(k)] bf16
    unsigned short* hbuf   = (unsigned short*)alloc(8388608);   // [B,N,C] bf16
    float* part            = (float*)alloc(512);                // GN stats [2][32][2]
    float* biasws          = (float*)alloc(4096);               // conv biases [2][512]

    dim3 blk(256);
    hipMemsetAsync(part, 0, 512, stream);
    cvt_all<<<2048, blk, 0, stream>>>(x, xb, pe, peb, qkv_w, qkvwb, proj_w, projwb,
                                      conv1_w, w1b, conv2_w, w2b, conv1_b, conv2_b, biasws);

    // conv1+conv2 in one launch (bz selects weights/bias/output); GN stats via atomics
    gemm_nt<0><<<dim3(512), blk, 0, stream>>>(peb, w1b, c1b, part, nullptr, biasws,
                                              512, 0, 262144, 4194304, 4, 64);
    gn_apply<<<1024, blk, 0, stream>>>(c1b, c2b, part, gn1_g, gn1_b, gn2_g, gn2_b);
    // qkv = x @ qkv_w.T -> q (x0.125*log2e), k [B,H,N,D]; vT [B,H,D,N] via LDS transpose
    gemm_qkv<<<dim3(768), blk, 0, stream>>>(xb, qkvwb, qbuf, kbuf, vtb);
    // pe_attn[b][n][m] = sigmoid(sum_k p1[n][k] p2[m][k])  ([q][k] orientation)
    gemm_nt<2><<<dim3(1024), blk, 0, stream>>>(c1b, c2b, peatt, nullptr, nullptr, nullptr,
                                               512, 1048576, 1048576, 4194304, 16, 16);
    attn_fused<<<dim3(512), dim3(512), 0, stream>>>(qbuf, kbuf, vtb, peatt, hbuf);
    // proj: out = h @ proj_w.T + proj_b (f32)
    gemm_nt<3><<<dim3(256), blk, 0, stream>>>(hbuf, projwb, out, nullptr, nullptr, proj_b,
                                              512, 0, 0, 0, 4, 64);
}